// Round 2
// baseline (409.884 us; speedup 1.0000x reference)
//
#include <hip/hip_runtime.h>
#include <hip/hip_bf16.h>

typedef __hip_bfloat16 bf16;
typedef __attribute__((ext_vector_type(8))) short bf16x8;
typedef __attribute__((ext_vector_type(4))) float f32x4;

constexpr int B_ = 32, S_ = 8, H_ = 32, W_ = 32, C_ = 128;
constexpr int NH_ = 8, KD_ = 512, DKH_ = 64, VF_ = 128, OF_ = 64;
constexpr int QKIN_ = 8192;

static __device__ __forceinline__ short bfbits(float f) {
    bf16 h = __float2bfloat16(f);
    short s;
    __builtin_memcpy(&s, &h, 2);
    return s;
}
static __device__ __forceinline__ unsigned int packbf2(float a, float b) {
    return ((unsigned int)(unsigned short)bfbits(b) << 16) | (unsigned short)bfbits(a);
}

// ---------------- prep device functions ----------------

// avg pool 4x4 -> flattened (img, 8192) bf16, float4 loads. idx in [0, n_img*2048)
static __device__ __forceinline__ void dev_pool4(const float* __restrict__ in,
                                                 short* __restrict__ out, int idx) {
    int c4 = (idx & 31) * 4;
    int pw = (idx >> 5) & 7;
    int ph = (idx >> 8) & 7;
    int img = idx >> 11;
    const float* p = in + (((size_t)img * H_ + ph * 4) * W_ + pw * 4) * C_ + c4;
    float4 s = {0.f, 0.f, 0.f, 0.f};
#pragma unroll
    for (int dy = 0; dy < 4; ++dy)
#pragma unroll
        for (int dx = 0; dx < 4; ++dx) {
            float4 v = *reinterpret_cast<const float4*>(p + (dy * W_ + dx) * C_);
            s.x += v.x; s.y += v.y; s.z += v.z; s.w += v.w;
        }
    uint2 pk;
    pk.x = packbf2(s.x * 0.0625f, s.y * 0.0625f);
    pk.y = packbf2(s.z * 0.0625f, s.w * 0.0625f);
    *reinterpret_cast<uint2*>(out + (size_t)img * QKIN_ + (ph * 8 + pw) * 128 + c4) = pk;
}

// transpose+cvt: w[K=8192][N=512] f32 -> wT[N][K] bf16. local in [0, 1024)
// Load phase: float4 per lane (1 KB per wave-instruction); LDS writes scalar
// (2-way bank alias = free). [65] pad keeps the read phase conflict-free.
static __device__ __forceinline__ void dev_wT(const float* __restrict__ w,
                                              short* __restrict__ wT, int local,
                                              float (*t)[65]) {
    int k0 = (local >> 3) * 64, n0 = (local & 7) * 64;
    int c4 = (threadIdx.x & 15) * 4, r16 = threadIdx.x >> 4;
#pragma unroll
    for (int i = 0; i < 4; ++i) {
        int kr = i * 16 + r16;
        float4 v = *reinterpret_cast<const float4*>(
            w + (size_t)(k0 + kr) * KD_ + n0 + c4);
        t[kr][c4 + 0] = v.x;
        t[kr][c4 + 1] = v.y;
        t[kr][c4 + 2] = v.z;
        t[kr][c4 + 3] = v.w;
    }
    __syncthreads();
    int n = threadIdx.x >> 3, kg = threadIdx.x & 7;
#pragma unroll
    for (int half = 0; half < 2; ++half) {
        int nn = n + half * 32;
        short v[8];
#pragma unroll
        for (int j = 0; j < 8; ++j) v[j] = bfbits(t[kg * 8 + j][nn]);
        *reinterpret_cast<bf16x8*>(wT + (size_t)(n0 + nn) * QKIN_ + k0 + kg * 8) =
            *reinterpret_cast<bf16x8*>(v);
    }
}

// conv weight transpose: [tap][ci][CO] f32 -> [tap][co][CI] bf16
static __device__ __forceinline__ void dev_wtrans(const float* __restrict__ in,
                                                  short* __restrict__ out, int idx,
                                                  int CO) {
    int tap = idx / (128 * CO);
    int rem = idx % (128 * CO);
    int co = rem / 128;
    int ci = rem & 127;
    out[idx] = bfbits(in[((size_t)tap * 128 + ci) * CO + co]);
}

// ---------------- merged prep: zero | pool(inp) | pool(k_ant) | wT(w_q) | wT(w_k)
//                  | wtrans_v | wtrans_o — all data-independent, one launch.
constexpr int PB_ZERO  = 144;              // 147456 floats, float4 stores
constexpr int PB_POOLI = PB_ZERO + 256;    // 32 imgs
constexpr int PB_POOLK = PB_POOLI + 2048;  // 256 imgs
constexpr int PB_WTQ   = PB_POOLK + 1024;
constexpr int PB_WTK   = PB_WTQ + 1024;
constexpr int PB_WV    = PB_WTK + 576;     // 9*128*128 elems
constexpr int PB_WO    = PB_WV + 288;      // 9*128*64 elems

__global__ __launch_bounds__(256) void k_prep(
    const float* __restrict__ inp, const float* __restrict__ k_ant,
    const float* __restrict__ w_q, const float* __restrict__ w_k,
    const float* __restrict__ cvw, const float* __restrict__ cow,
    float* __restrict__ qk_zero, short* __restrict__ q_a, short* __restrict__ k_a,
    short* __restrict__ wqT, short* __restrict__ wkT,
    short* __restrict__ wvT, short* __restrict__ woT) {
    __shared__ float t[64][65];
    int bx = blockIdx.x;
    if (bx < PB_ZERO) {
        int i = (bx * 256 + threadIdx.x) * 4;
        float4 z = {0.f, 0.f, 0.f, 0.f};
        *reinterpret_cast<float4*>(qk_zero + i) = z;
    } else if (bx < PB_POOLI) {
        dev_pool4(inp, q_a, (bx - PB_ZERO) * 256 + threadIdx.x);
    } else if (bx < PB_POOLK) {
        dev_pool4(k_ant, k_a, (bx - PB_POOLI) * 256 + threadIdx.x);
    } else if (bx < PB_WTK) {
        if (bx < PB_WTQ)
            dev_wT(w_q, wqT, bx - PB_POOLK, t);
        else
            dev_wT(w_k, wkT, bx - PB_WTQ, t);
    } else if (bx < PB_WV) {
        dev_wtrans(cvw, wvT, (bx - PB_WTK) * 256 + threadIdx.x, 128);
    } else {
        dev_wtrans(cow, woT, (bx - PB_WV) * 256 + threadIdx.x, 64);
    }
}

// ---------------- merged MFMA GEMM: q (M=32) and k (M=256), K-split 16 (tile 512).
// 64 q-blocks + 512 k-blocks = 576 blocks -> 2.25 blocks/CU (2 waves/SIMD).
__global__ __launch_bounds__(256) void k_gemm2(
    const short* __restrict__ qa, const short* __restrict__ ka,
    const short* __restrict__ wqTp, const short* __restrict__ wkTp,
    float* __restrict__ qo, float* __restrict__ ko) {
    int wave = threadIdx.x >> 6, lane = threadIdx.x & 63;
    int quad = lane >> 4, l15 = lane & 15;
    int id = blockIdx.x;
    const short* A;
    const short* WT;
    float* out;
    int m0, rem;
    if (id < 64) {
        A = qa; WT = wqTp; out = qo; m0 = 0; rem = id;
    } else {
        id -= 64;
        A = ka; WT = wkTp; out = ko;
        m0 = (id >> 6) * 32; rem = id & 63;
    }
    int n0 = (rem & 3) * 128 + wave * 32;
    int k0 = (rem >> 2) * 512;
    f32x4 acc[2][2];
#pragma unroll
    for (int mt = 0; mt < 2; ++mt)
#pragma unroll
        for (int nt = 0; nt < 2; ++nt) acc[mt][nt] = (f32x4){0.f, 0.f, 0.f, 0.f};
    const short* a0p = A + (size_t)(m0 + l15) * QKIN_;
    const short* a1p = a0p + 16 * QKIN_;
    const short* b0p = WT + (size_t)(n0 + l15) * QKIN_;
    const short* b1p = b0p + 16 * QKIN_;
    for (int kk = k0 + quad * 8; kk < k0 + 512; kk += 32) {
        bf16x8 a0 = *reinterpret_cast<const bf16x8*>(a0p + kk);
        bf16x8 a1 = *reinterpret_cast<const bf16x8*>(a1p + kk);
        bf16x8 b0 = *reinterpret_cast<const bf16x8*>(b0p + kk);
        bf16x8 b1 = *reinterpret_cast<const bf16x8*>(b1p + kk);
        acc[0][0] = __builtin_amdgcn_mfma_f32_16x16x32_bf16(a0, b0, acc[0][0], 0, 0, 0);
        acc[0][1] = __builtin_amdgcn_mfma_f32_16x16x32_bf16(a0, b1, acc[0][1], 0, 0, 0);
        acc[1][0] = __builtin_amdgcn_mfma_f32_16x16x32_bf16(a1, b0, acc[1][0], 0, 0, 0);
        acc[1][1] = __builtin_amdgcn_mfma_f32_16x16x32_bf16(a1, b1, acc[1][1], 0, 0, 0);
    }
#pragma unroll
    for (int mt = 0; mt < 2; ++mt)
#pragma unroll
        for (int nt = 0; nt < 2; ++nt)
#pragma unroll
            for (int reg = 0; reg < 4; ++reg)
                atomicAdd(&out[(size_t)(m0 + mt * 16 + quad * 4 + reg) * KD_ +
                               n0 + nt * 16 + l15],
                          acc[mt][nt][reg]);
}

// ---------------- fused softmax + mix + conv_v via MFMA.
// 2-row groups: block=(b, rg of 16), 512 blocks -> 2 blocks/CU so the HBM
// strip-mix phase of one block overlaps the MFMA phase of its neighbor.
__global__ __launch_bounds__(256) void k_convv_mfma(
    const float* __restrict__ v_ant, const short* __restrict__ wvT,
    const float* __restrict__ bias, const float* __restrict__ tbv,
    const float* __restrict__ q, const float* __restrict__ kmat,
    const float* __restrict__ tbk, short* __restrict__ x) {
    __shared__ short strip[4 * 34 * 136];  // 36992 B
    __shared__ float w8s[8];
    int bx = blockIdx.x;
    int b = bx >> 4, rg = bx & 15;
    int y0 = rg * 2;
    int h = rg >> 1;
    // phase 0: in-block softmax over s for (b,h) — wave 0, 64-lane butterfly dot
    if (threadIdx.x < 64) {
        int d = threadIdx.x;
        float qv = q[(size_t)b * KD_ + h * DKH_ + d];
        float lg[8];
        float m = -1e30f;
#pragma unroll
        for (int s = 0; s < 8; ++s) {
            int zi = (s < 4) ? 0 : (s - 4);
            float kv = kmat[((size_t)b * S_ + s) * KD_ + h * DKH_ + d] + tbk[zi * DKH_ + d];
            float p = qv * kv * 0.125f;
#pragma unroll
            for (int msk = 1; msk < 64; msk <<= 1) p += __shfl_xor(p, msk);
            lg[s] = p;
            m = fmaxf(m, p);
        }
        float sum = 0.f;
#pragma unroll
        for (int s = 0; s < 8; ++s) {
            lg[s] = expf(lg[s] - m);
            sum += lg[s];
        }
        if (d == 0) {
            float inv = 1.f / sum;
#pragma unroll
            for (int s = 0; s < 8; ++s) w8s[s] = lg[s] * inv;
        }
    }
    // zero the px=-1 / px=32 halo columns (4 rows x 2 sides x 32 cg = 256)
    {
        int i = threadIdx.x;
        int r = i >> 6, remz = i & 63;
        int side = remz >> 5, cg = remz & 31;
        uint2 z = {0u, 0u};
        *reinterpret_cast<uint2*>(&strip[(r * 34 + side * 33) * 136 + cg * 4]) = z;
    }
    __syncthreads();
    float w8[8];
#pragma unroll
    for (int kk = 0; kk < 8; ++kk) w8[kk] = w8s[kk];
    // phase 1: softmax-mix 4 halo rows -> bf16 strip (float4 loads)
    for (int i = threadIdx.x; i < 4 * 1024; i += 256) {
        int r = i >> 10, rem = i & 1023;  // rem = px*32 + ci/4
        int yimg = y0 - 1 + r;
        float4 s = {0.f, 0.f, 0.f, 0.f};
        if (0 <= yimg && yimg < H_) {
            const float* base = v_ant + (size_t)b * 1048576 + yimg * 4096 + rem * 4;
#pragma unroll
            for (int kk = 0; kk < 8; ++kk) {
                float4 v = *reinterpret_cast<const float4*>(base + (size_t)kk * 131072);
                s.x = fmaf(w8[kk], v.x, s.x);
                s.y = fmaf(w8[kk], v.y, s.y);
                s.z = fmaf(w8[kk], v.z, s.z);
                s.w = fmaf(w8[kk], v.w, s.w);
            }
        }
        int px = rem >> 5, cg = rem & 31;
        uint2 pk;
        pk.x = packbf2(s.x, s.y);
        pk.y = packbf2(s.z, s.w);
        *reinterpret_cast<uint2*>(&strip[(r * 34 + px + 1) * 136 + cg * 4]) = pk;
    }
    __syncthreads();
    // phase 2: GEMM M=64(2 rows x 32 px), N=128 co, K=1152
    int wave = threadIdx.x >> 6, lane = threadIdx.x & 63;
    int quad = lane >> 4, l15 = lane & 15;
    int n0 = wave * 32;
    f32x4 acc[4][2];
#pragma unroll
    for (int mt = 0; mt < 4; ++mt)
#pragma unroll
        for (int nt = 0; nt < 2; ++nt) acc[mt][nt] = (f32x4){0.f, 0.f, 0.f, 0.f};
    for (int kc = 0; kc < 36; ++kc) {
        int tap = kc >> 2;
        int ci0 = (kc & 3) * 32 + quad * 8;
        int ky = tap / 3, dx = tap % 3;
        bf16x8 bfr[2];
#pragma unroll
        for (int nt = 0; nt < 2; ++nt) {
            int co = n0 + nt * 16 + l15;
            bfr[nt] = *reinterpret_cast<const bf16x8*>(
                wvT + ((size_t)tap * 128 + co) * 128 + ci0);
        }
#pragma unroll
        for (int mt = 0; mt < 4; ++mt) {
            int jout = mt >> 1, half = mt & 1;
            int r = jout + ky;
            int px1 = half * 16 + l15 + dx;  // 0..33, in-bounds by padding
            bf16x8 afr = *reinterpret_cast<const bf16x8*>(
                &strip[(r * 34 + px1) * 136 + ci0]);
            acc[mt][0] = __builtin_amdgcn_mfma_f32_16x16x32_bf16(afr, bfr[0], acc[mt][0], 0, 0, 0);
            acc[mt][1] = __builtin_amdgcn_mfma_f32_16x16x32_bf16(afr, bfr[1], acc[mt][1], 0, 0, 0);
        }
    }
    float cw[4];
    cw[0] = w8[0] + w8[1] + w8[2] + w8[3] + w8[4];
    cw[1] = w8[5];
    cw[2] = w8[6];
    cw[3] = w8[7];
#pragma unroll
    for (int mt = 0; mt < 4; ++mt) {
        int jout = mt >> 1, half = mt & 1;
        int y = y0 + jout;
        int dbase = (y & 3) * 4096;  // row index within this head's 4-row slice
#pragma unroll
        for (int nt = 0; nt < 2; ++nt) {
            int co = n0 + nt * 16 + l15;
            float bv = bias[co];
#pragma unroll
            for (int reg = 0; reg < 4; ++reg) {
                int px = half * 16 + quad * 4 + reg;
                int d = dbase + px * 128 + co;
                float v = acc[mt][nt][reg] + bv;
                v = fmaf(cw[0], tbv[d], v);
                v = fmaf(cw[1], tbv[16384 + d], v);
                v = fmaf(cw[2], tbv[32768 + d], v);
                v = fmaf(cw[3], tbv[49152 + d], v);
                x[(((size_t)b * H_ + y) * W_ + px) * C_ + co] = bfbits(v);
            }
        }
    }
}

// ---------------- conv_o via MFMA. 2-row groups: block=(b, rg of 16), 512 blocks.
__global__ __launch_bounds__(256) void k_convo_mfma(
    const short* __restrict__ x, const short* __restrict__ woT,
    const float* __restrict__ bias, float* __restrict__ out) {
    __shared__ short strip[4 * 34 * 136];
    int bx = blockIdx.x;
    int b = bx >> 4, rg = bx & 15;
    int y0 = rg * 2;
    {
        int i = threadIdx.x;
        int r = i >> 6, remz = i & 63;
        int side = remz >> 5, cg = remz & 31;
        uint2 z = {0u, 0u};
        *reinterpret_cast<uint2*>(&strip[(r * 34 + side * 33) * 136 + cg * 4]) = z;
    }
    for (int i = threadIdx.x; i < 4 * 1024; i += 256) {
        int r = i >> 10, rem = i & 1023;
        int yimg = y0 - 1 + r;
        uint2 v = {0u, 0u};
        if (0 <= yimg && yimg < H_)
            v = *reinterpret_cast<const uint2*>(
                x + (size_t)b * 131072 + yimg * 4096 + rem * 4);
        int px = rem >> 5, cg = rem & 31;
        *reinterpret_cast<uint2*>(&strip[(r * 34 + px + 1) * 136 + cg * 4]) = v;
    }
    __syncthreads();
    int wave = threadIdx.x >> 6, lane = threadIdx.x & 63;
    int quad = lane >> 4, l15 = lane & 15;
    int co = wave * 16 + l15;
    f32x4 acc[4];
#pragma unroll
    for (int mt = 0; mt < 4; ++mt) acc[mt] = (f32x4){0.f, 0.f, 0.f, 0.f};
    for (int kc = 0; kc < 36; ++kc) {
        int tap = kc >> 2;
        int ci0 = (kc & 3) * 32 + quad * 8;
        int ky = tap / 3, dx = tap % 3;
        bf16x8 bfr = *reinterpret_cast<const bf16x8*>(
            woT + ((size_t)tap * 64 + co) * 128 + ci0);
#pragma unroll
        for (int mt = 0; mt < 4; ++mt) {
            int jout = mt >> 1, half = mt & 1;
            int r = jout + ky;
            int px1 = half * 16 + l15 + dx;
            bf16x8 afr = *reinterpret_cast<const bf16x8*>(
                &strip[(r * 34 + px1) * 136 + ci0]);
            acc[mt] = __builtin_amdgcn_mfma_f32_16x16x32_bf16(afr, bfr, acc[mt], 0, 0, 0);
        }
    }
    float bv = bias[co];
#pragma unroll
    for (int mt = 0; mt < 4; ++mt) {
        int jout = mt >> 1, half = mt & 1;
#pragma unroll
        for (int reg = 0; reg < 4; ++reg) {
            int px = half * 16 + quad * 4 + reg;
            out[(((size_t)b * H_ + y0 + jout) * W_ + px) * OF_ + co] = acc[mt][reg] + bv;
        }
    }
}

extern "C" void kernel_launch(void* const* d_in, const int* in_sizes, int n_in,
                              void* d_out, int out_size, void* d_ws, size_t ws_size,
                              hipStream_t stream) {
    const float* inp   = (const float*)d_in[0];
    const float* k_ant = (const float*)d_in[1];
    const float* v_ant = (const float*)d_in[2];
    const float* w_q   = (const float*)d_in[3];
    const float* w_k   = (const float*)d_in[4];
    const float* cvw   = (const float*)d_in[5];
    const float* cvb   = (const float*)d_in[6];
    const float* cow   = (const float*)d_in[7];
    const float* cob   = (const float*)d_in[8];
    const float* tbk   = (const float*)d_in[9];
    const float* tbv   = (const float*)d_in[10];

    // ws layout (bytes). x aliases wqT (wqT's last read — the q GEMM — precedes
    // x's first write in stream order).
    char* wsb = (char*)d_ws;
    float* q    = (float*)(wsb + 0);         //   16384 f32
    float* k    = (float*)(wsb + 65536);     //  131072 f32
    short* q_a  = (short*)(wsb + 598016);    //  262144 bf16
    short* k_a  = (short*)(wsb + 1122304);   // 2097152 bf16
    short* wvT  = (short*)(wsb + 5316608);   //  147456 bf16
    short* woT  = (short*)(wsb + 5611520);   //   73728 bf16
    short* wkT  = (short*)(wsb + 5758976);   // 4194304 bf16
    short* wqT  = (short*)(wsb + 14147584);  // 4194304 bf16
    short* x    = wqT;                       // alias (see above)

    k_prep<<<PB_WO, 256, 0, stream>>>(inp, k_ant, w_q, w_k, cvw, cow,
                                      q, q_a, k_a, wqT, wkT, wvT, woT);
    k_gemm2<<<576, 256, 0, stream>>>(q_a, k_a, wqT, wkT, q, k);
    k_convv_mfma<<<512, 256, 0, stream>>>(v_ant, wvT, cvb, tbv, q, k, tbk, x);
    k_convo_mfma<<<512, 256, 0, stream>>>(x, woT, cob, (float*)d_out);
}

// Round 4
// 402.691 us; speedup vs baseline: 1.0179x; 1.0179x over previous
//
#include <hip/hip_runtime.h>
#include <hip/hip_bf16.h>

typedef __hip_bfloat16 bf16;
typedef __attribute__((ext_vector_type(8))) short bf16x8;
typedef __attribute__((ext_vector_type(4))) float f32x4;

constexpr int B_ = 32, S_ = 8, H_ = 32, W_ = 32, C_ = 128;
constexpr int NH_ = 8, KD_ = 512, DKH_ = 64, VF_ = 128, OF_ = 64;
constexpr int QKIN_ = 8192;

static __device__ __forceinline__ short bfbits(float f) {
    bf16 h = __float2bfloat16(f);
    short s;
    __builtin_memcpy(&s, &h, 2);
    return s;
}
static __device__ __forceinline__ unsigned int packbf2(float a, float b) {
    return ((unsigned int)(unsigned short)bfbits(b) << 16) | (unsigned short)bfbits(a);
}

// ---------------- prep device functions ----------------

// avg pool 4x4 -> flattened (img, 8192) bf16. Two batches of 8 explicit float4
// loads so 8 are in flight (serial load->fmaf chains are latency killers).
static __device__ __forceinline__ void dev_pool4(const float* __restrict__ in,
                                                 short* __restrict__ out, int idx) {
    int c4 = (idx & 31) * 4;
    int pw = (idx >> 5) & 7;
    int ph = (idx >> 8) & 7;
    int img = idx >> 11;
    const float* p = in + (((size_t)img * H_ + ph * 4) * W_ + pw * 4) * C_ + c4;
    float4 s = {0.f, 0.f, 0.f, 0.f};
#pragma unroll
    for (int half = 0; half < 2; ++half) {
        float4 v[8];
#pragma unroll
        for (int j = 0; j < 8; ++j) {
            int dy = half * 2 + (j >> 2), dx = j & 3;
            v[j] = *reinterpret_cast<const float4*>(p + (dy * W_ + dx) * C_);
        }
#pragma unroll
        for (int j = 0; j < 8; ++j) {
            s.x += v[j].x; s.y += v[j].y; s.z += v[j].z; s.w += v[j].w;
        }
    }
    uint2 pk;
    pk.x = packbf2(s.x * 0.0625f, s.y * 0.0625f);
    pk.y = packbf2(s.z * 0.0625f, s.w * 0.0625f);
    *reinterpret_cast<uint2*>(out + (size_t)img * QKIN_ + (ph * 8 + pw) * 128 + c4) = pk;
}

// transpose+cvt: w[K=8192][N=512] f32 -> wT[N][K] bf16. local in [0, 1024)
static __device__ __forceinline__ void dev_wT(const float* __restrict__ w,
                                              short* __restrict__ wT, int local,
                                              float (*t)[65]) {
    int k0 = (local >> 3) * 64, n0 = (local & 7) * 64;
    int c4 = (threadIdx.x & 15) * 4, r16 = threadIdx.x >> 4;
#pragma unroll
    for (int i = 0; i < 4; ++i) {
        int kr = i * 16 + r16;
        float4 v = *reinterpret_cast<const float4*>(
            w + (size_t)(k0 + kr) * KD_ + n0 + c4);
        t[kr][c4 + 0] = v.x;
        t[kr][c4 + 1] = v.y;
        t[kr][c4 + 2] = v.z;
        t[kr][c4 + 3] = v.w;
    }
    __syncthreads();
    int n = threadIdx.x >> 3, kg = threadIdx.x & 7;
#pragma unroll
    for (int half = 0; half < 2; ++half) {
        int nn = n + half * 32;
        short v[8];
#pragma unroll
        for (int j = 0; j < 8; ++j) v[j] = bfbits(t[kg * 8 + j][nn]);
        *reinterpret_cast<bf16x8*>(wT + (size_t)(n0 + nn) * QKIN_ + k0 + kg * 8) =
            *reinterpret_cast<bf16x8*>(v);
    }
}

// conv weight transpose: [tap][ci][CO] f32 -> [tap][co][CI] bf16
static __device__ __forceinline__ void dev_wtrans(const float* __restrict__ in,
                                                  short* __restrict__ out, int idx,
                                                  int CO) {
    int tap = idx / (128 * CO);
    int rem = idx % (128 * CO);
    int co = rem / 128;
    int ci = rem & 127;
    out[idx] = bfbits(in[((size_t)tap * 128 + ci) * CO + co]);
}

// ---------------- merged prep
constexpr int PB_ZERO  = 144;
constexpr int PB_POOLI = PB_ZERO + 256;
constexpr int PB_POOLK = PB_POOLI + 2048;
constexpr int PB_WTQ   = PB_POOLK + 1024;
constexpr int PB_WTK   = PB_WTQ + 1024;
constexpr int PB_WV    = PB_WTK + 576;
constexpr int PB_WO    = PB_WV + 288;

__global__ __launch_bounds__(256) void k_prep(
    const float* __restrict__ inp, const float* __restrict__ k_ant,
    const float* __restrict__ w_q, const float* __restrict__ w_k,
    const float* __restrict__ cvw, const float* __restrict__ cow,
    float* __restrict__ qk_zero, short* __restrict__ q_a, short* __restrict__ k_a,
    short* __restrict__ wqT, short* __restrict__ wkT,
    short* __restrict__ wvT, short* __restrict__ woT) {
    __shared__ float t[64][65];
    int bx = blockIdx.x;
    if (bx < PB_ZERO) {
        int i = (bx * 256 + threadIdx.x) * 4;
        float4 z = {0.f, 0.f, 0.f, 0.f};
        *reinterpret_cast<float4*>(qk_zero + i) = z;
    } else if (bx < PB_POOLI) {
        dev_pool4(inp, q_a, (bx - PB_ZERO) * 256 + threadIdx.x);
    } else if (bx < PB_POOLK) {
        dev_pool4(k_ant, k_a, (bx - PB_POOLI) * 256 + threadIdx.x);
    } else if (bx < PB_WTK) {
        if (bx < PB_WTQ)
            dev_wT(w_q, wqT, bx - PB_POOLK, t);
        else
            dev_wT(w_k, wkT, bx - PB_WTQ, t);
    } else if (bx < PB_WV) {
        dev_wtrans(cvw, wvT, (bx - PB_WTK) * 256 + threadIdx.x, 128);
    } else {
        dev_wtrans(cow, woT, (bx - PB_WV) * 256 + threadIdx.x, 64);
    }
}

// ---------------- merged MFMA GEMM: q (M=32) and k (M=256), K-split 16.
__global__ __launch_bounds__(256) void k_gemm2(
    const short* __restrict__ qa, const short* __restrict__ ka,
    const short* __restrict__ wqTp, const short* __restrict__ wkTp,
    float* __restrict__ qo, float* __restrict__ ko) {
    int wave = threadIdx.x >> 6, lane = threadIdx.x & 63;
    int quad = lane >> 4, l15 = lane & 15;
    int id = blockIdx.x;
    const short* A;
    const short* WT;
    float* out;
    int m0, rem;
    if (id < 64) {
        A = qa; WT = wqTp; out = qo; m0 = 0; rem = id;
    } else {
        id -= 64;
        A = ka; WT = wkTp; out = ko;
        m0 = (id >> 6) * 32; rem = id & 63;
    }
    int n0 = (rem & 3) * 128 + wave * 32;
    int k0 = (rem >> 2) * 512;
    f32x4 acc[2][2];
#pragma unroll
    for (int mt = 0; mt < 2; ++mt)
#pragma unroll
        for (int nt = 0; nt < 2; ++nt) acc[mt][nt] = (f32x4){0.f, 0.f, 0.f, 0.f};
    const short* a0p = A + (size_t)(m0 + l15) * QKIN_;
    const short* a1p = a0p + 16 * QKIN_;
    const short* b0p = WT + (size_t)(n0 + l15) * QKIN_;
    const short* b1p = b0p + 16 * QKIN_;
    for (int kk = k0 + quad * 8; kk < k0 + 512; kk += 32) {
        bf16x8 a0 = *reinterpret_cast<const bf16x8*>(a0p + kk);
        bf16x8 a1 = *reinterpret_cast<const bf16x8*>(a1p + kk);
        bf16x8 b0 = *reinterpret_cast<const bf16x8*>(b0p + kk);
        bf16x8 b1 = *reinterpret_cast<const bf16x8*>(b1p + kk);
        acc[0][0] = __builtin_amdgcn_mfma_f32_16x16x32_bf16(a0, b0, acc[0][0], 0, 0, 0);
        acc[0][1] = __builtin_amdgcn_mfma_f32_16x16x32_bf16(a0, b1, acc[0][1], 0, 0, 0);
        acc[1][0] = __builtin_amdgcn_mfma_f32_16x16x32_bf16(a1, b0, acc[1][0], 0, 0, 0);
        acc[1][1] = __builtin_amdgcn_mfma_f32_16x16x32_bf16(a1, b1, acc[1][1], 0, 0, 0);
    }
#pragma unroll
    for (int mt = 0; mt < 2; ++mt)
#pragma unroll
        for (int nt = 0; nt < 2; ++nt)
#pragma unroll
            for (int reg = 0; reg < 4; ++reg)
                atomicAdd(&out[(size_t)(m0 + mt * 16 + quad * 4 + reg) * KD_ +
                               n0 + nt * 16 + l15],
                          acc[mt][nt][reg]);
}

// ---------------- softmax helper: wave 0 computes w8s[8] for (b,h)
static __device__ __forceinline__ void dev_softmax(
    const float* __restrict__ q, const float* __restrict__ kmat,
    const float* __restrict__ tbk, int b, int h, float* w8s) {
    if (threadIdx.x < 64) {
        int d = threadIdx.x;
        float qv = q[(size_t)b * KD_ + h * DKH_ + d];
        float lg[8];
        float m = -1e30f;
#pragma unroll
        for (int s = 0; s < 8; ++s) {
            int zi = (s < 4) ? 0 : (s - 4);
            float kv = kmat[((size_t)b * S_ + s) * KD_ + h * DKH_ + d] + tbk[zi * DKH_ + d];
            float p = qv * kv * 0.125f;
#pragma unroll
            for (int msk = 1; msk < 64; msk <<= 1) p += __shfl_xor(p, msk);
            lg[s] = p;
            m = fmaxf(m, p);
        }
        float sum = 0.f;
#pragma unroll
        for (int s = 0; s < 8; ++s) {
            lg[s] = expf(lg[s] - m);
            sum += lg[s];
        }
        if (d == 0) {
            float inv = 1.f / sum;
#pragma unroll
            for (int s = 0; s < 8; ++s) w8s[s] = lg[s] * inv;
        }
    }
}

// ---------------- k_mix: streaming softmax-mix of v_ant into PER-HEAD 6-row
// halo strips: xmix[b][h][r] = row (4h-1+r) mixed with head h's weights.
// (Halo rows must be mixed with the CONSUMING head's weights — head-boundary
// rows need two differently-weighted copies, hence per-head strips.)
// block = (b, h, r): 1536 blocks, 8 explicit loads in flight, no LDS tile.
__global__ __launch_bounds__(256) void k_mix(
    const float* __restrict__ v_ant, const float* __restrict__ q,
    const float* __restrict__ kmat, const float* __restrict__ tbk,
    short* __restrict__ xmix) {
    __shared__ float w8s[8];
    int bx = blockIdx.x;
    int b = bx / 48;
    int rem6 = bx % 48;
    int h = rem6 / 6, r = rem6 % 6;
    dev_softmax(q, kmat, tbk, b, h, w8s);
    __syncthreads();
    int yimg = 4 * h - 1 + r;
    short* outp = xmix + ((size_t)(b * 8 + h) * 6 + r) * 4096;
    if (yimg < 0 || yimg >= H_) {
        uint2 z = {0u, 0u};
#pragma unroll
        for (int it = 0; it < 4; ++it) {
            int off = (it * 256 + threadIdx.x) * 4;
            *reinterpret_cast<uint2*>(outp + off) = z;
        }
        return;
    }
    float w8[8];
#pragma unroll
    for (int s = 0; s < 8; ++s) w8[s] = w8s[s];
    const float* base0 = v_ant + (size_t)b * 1048576 + yimg * 4096;
#pragma unroll
    for (int it = 0; it < 4; ++it) {
        int off = (it * 256 + threadIdx.x) * 4;  // px*128 + c4
        float4 v[8];
#pragma unroll
        for (int s = 0; s < 8; ++s)
            v[s] = *reinterpret_cast<const float4*>(base0 + (size_t)s * 131072 + off);
        float4 a = {0.f, 0.f, 0.f, 0.f};
#pragma unroll
        for (int s = 0; s < 8; ++s) {
            a.x = fmaf(w8[s], v[s].x, a.x);
            a.y = fmaf(w8[s], v[s].y, a.y);
            a.z = fmaf(w8[s], v[s].z, a.z);
            a.w = fmaf(w8[s], v[s].w, a.w);
        }
        uint2 pk;
        pk.x = packbf2(a.x, a.y);
        pk.y = packbf2(a.z, a.w);
        *reinterpret_cast<uint2*>(outp + off) = pk;
    }
}

// ---------------- staging: contiguous 6-row pre-mixed strip -> padded LDS strip.
// Unconditional loads (halo rows pre-zeroed in xmix), 3 rounds x 8 in flight.
static __device__ __forceinline__ void dev_stage_copy(const short* __restrict__ src,
                                                      short* __restrict__ strip) {
    for (int i = threadIdx.x; i < 384; i += 256) {
        int r = i >> 6, remz = i & 63;
        int side = remz >> 5, cg = remz & 31;
        uint2 z = {0u, 0u};
        *reinterpret_cast<uint2*>(&strip[(r * 34 + side * 33) * 136 + cg * 4]) = z;
    }
#pragma unroll
    for (int round = 0; round < 3; ++round) {
        uint2 vv[8];
#pragma unroll
        for (int j = 0; j < 8; ++j) {
            int i = (round * 8 + j) * 256 + threadIdx.x;
            vv[j] = *reinterpret_cast<const uint2*>(src + i * 4);
        }
#pragma unroll
        for (int j = 0; j < 8; ++j) {
            int i = (round * 8 + j) * 256 + threadIdx.x;
            int r = i >> 10, rem = i & 1023;
            int px = rem >> 5, cg = rem & 31;
            *reinterpret_cast<uint2*>(&strip[(r * 34 + px + 1) * 136 + cg * 4]) = vv[j];
        }
    }
}

// ---------------- strip staging with row-bounds checks (for conv_o over x).
static __device__ __forceinline__ void dev_stage6(const short* __restrict__ src,
                                                  int y0, short* __restrict__ strip) {
    for (int i = threadIdx.x; i < 384; i += 256) {
        int r = i >> 6, remz = i & 63;
        int side = remz >> 5, cg = remz & 31;
        uint2 z = {0u, 0u};
        *reinterpret_cast<uint2*>(&strip[(r * 34 + side * 33) * 136 + cg * 4]) = z;
    }
#pragma unroll
    for (int round = 0; round < 3; ++round) {
        uint2 vv[8];
#pragma unroll
        for (int j = 0; j < 8; ++j) {
            int i = (round * 8 + j) * 256 + threadIdx.x;
            int r = i >> 10, rem = i & 1023;
            int yimg = y0 - 1 + r;
            vv[j] = (uint2){0u, 0u};
            if (0 <= yimg && yimg < H_)
                vv[j] = *reinterpret_cast<const uint2*>(src + yimg * 4096 + rem * 4);
        }
#pragma unroll
        for (int j = 0; j < 8; ++j) {
            int i = (round * 8 + j) * 256 + threadIdx.x;
            int r = i >> 10, rem = i & 1023;
            int px = rem >> 5, cg = rem & 31;
            *reinterpret_cast<uint2*>(&strip[(r * 34 + px + 1) * 136 + cg * 4]) = vv[j];
        }
    }
}

// ---------------- conv_v GEMM over per-head pre-mixed strips. block=(b,h).
__global__ __launch_bounds__(256) void k_convv2(
    const short* __restrict__ xmix, const short* __restrict__ wvT,
    const float* __restrict__ bias, const float* __restrict__ tbv,
    const float* __restrict__ q, const float* __restrict__ kmat,
    const float* __restrict__ tbk, short* __restrict__ x) {
    __shared__ short strip[6 * 34 * 136];  // 55488 B
    __shared__ float w8s[8];
    int b = blockIdx.x >> 3, h = blockIdx.x & 7;
    int y0 = 4 * h;
    dev_softmax(q, kmat, tbk, b, h, w8s);
    dev_stage_copy(xmix + (size_t)(b * 8 + h) * 6 * 4096, strip);
    __syncthreads();
    int wave = threadIdx.x >> 6, lane = threadIdx.x & 63;
    int quad = lane >> 4, l15 = lane & 15;
    int n0 = wave * 32;
    f32x4 acc[8][2];
#pragma unroll
    for (int mt = 0; mt < 8; ++mt)
#pragma unroll
        for (int nt = 0; nt < 2; ++nt) acc[mt][nt] = (f32x4){0.f, 0.f, 0.f, 0.f};
    for (int kc = 0; kc < 36; ++kc) {
        int tap = kc >> 2;
        int ci0 = (kc & 3) * 32 + quad * 8;
        int ky = tap / 3, dx = tap % 3;
        bf16x8 bfr[2];
#pragma unroll
        for (int nt = 0; nt < 2; ++nt) {
            int co = n0 + nt * 16 + l15;
            bfr[nt] = *reinterpret_cast<const bf16x8*>(
                wvT + ((size_t)tap * 128 + co) * 128 + ci0);
        }
#pragma unroll
        for (int mt = 0; mt < 8; ++mt) {
            int jout = mt >> 1, half = mt & 1;
            int r = jout + ky;
            int px1 = half * 16 + l15 + dx;
            bf16x8 afr = *reinterpret_cast<const bf16x8*>(
                &strip[(r * 34 + px1) * 136 + ci0]);
            acc[mt][0] = __builtin_amdgcn_mfma_f32_16x16x32_bf16(afr, bfr[0], acc[mt][0], 0, 0, 0);
            acc[mt][1] = __builtin_amdgcn_mfma_f32_16x16x32_bf16(afr, bfr[1], acc[mt][1], 0, 0, 0);
        }
    }
    float cw[4];
    cw[0] = w8s[0] + w8s[1] + w8s[2] + w8s[3] + w8s[4];
    cw[1] = w8s[5];
    cw[2] = w8s[6];
    cw[3] = w8s[7];
#pragma unroll
    for (int mt = 0; mt < 8; ++mt) {
        int jout = mt >> 1, half = mt & 1;
#pragma unroll
        for (int nt = 0; nt < 2; ++nt) {
            int co = n0 + nt * 16 + l15;
            float bv = bias[co];
#pragma unroll
            for (int reg = 0; reg < 4; ++reg) {
                int px = half * 16 + quad * 4 + reg;
                int d = jout * 4096 + px * 128 + co;
                float v = acc[mt][nt][reg] + bv;
                v = fmaf(cw[0], tbv[d], v);
                v = fmaf(cw[1], tbv[16384 + d], v);
                v = fmaf(cw[2], tbv[32768 + d], v);
                v = fmaf(cw[3], tbv[49152 + d], v);
                x[(((size_t)b * H_ + y0 + jout) * W_ + px) * C_ + co] = bfbits(v);
            }
        }
    }
}

// ---------------- conv_o via MFMA. block=(b, rowgroup of 4), 4-row groups.
__global__ __launch_bounds__(256) void k_convo_mfma(
    const short* __restrict__ x, const short* __restrict__ woT,
    const float* __restrict__ bias, float* __restrict__ out) {
    __shared__ short strip[6 * 34 * 136];
    int b = blockIdx.x >> 3, rg = blockIdx.x & 7;
    int y0 = 4 * rg;
    dev_stage6(x + (size_t)b * 131072, y0, strip);
    __syncthreads();
    int wave = threadIdx.x >> 6, lane = threadIdx.x & 63;
    int quad = lane >> 4, l15 = lane & 15;
    int co = wave * 16 + l15;
    f32x4 acc[8];
#pragma unroll
    for (int mt = 0; mt < 8; ++mt) acc[mt] = (f32x4){0.f, 0.f, 0.f, 0.f};
    for (int kc = 0; kc < 36; ++kc) {
        int tap = kc >> 2;
        int ci0 = (kc & 3) * 32 + quad * 8;
        int ky = tap / 3, dx = tap % 3;
        bf16x8 bfr = *reinterpret_cast<const bf16x8*>(
            woT + ((size_t)tap * 64 + co) * 128 + ci0);
#pragma unroll
        for (int mt = 0; mt < 8; ++mt) {
            int jout = mt >> 1, half = mt & 1;
            int r = jout + ky;
            int px1 = half * 16 + l15 + dx;
            bf16x8 afr = *reinterpret_cast<const bf16x8*>(
                &strip[(r * 34 + px1) * 136 + ci0]);
            acc[mt] = __builtin_amdgcn_mfma_f32_16x16x32_bf16(afr, bfr, acc[mt], 0, 0, 0);
        }
    }
    float bv = bias[co];
#pragma unroll
    for (int mt = 0; mt < 8; ++mt) {
        int jout = mt >> 1, half = mt & 1;
#pragma unroll
        for (int reg = 0; reg < 4; ++reg) {
            int px = half * 16 + quad * 4 + reg;
            out[(((size_t)b * H_ + y0 + jout) * W_ + px) * OF_ + co] = acc[mt][reg] + bv;
        }
    }
}

extern "C" void kernel_launch(void* const* d_in, const int* in_sizes, int n_in,
                              void* d_out, int out_size, void* d_ws, size_t ws_size,
                              hipStream_t stream) {
    const float* inp   = (const float*)d_in[0];
    const float* k_ant = (const float*)d_in[1];
    const float* v_ant = (const float*)d_in[2];
    const float* w_q   = (const float*)d_in[3];
    const float* w_k   = (const float*)d_in[4];
    const float* cvw   = (const float*)d_in[5];
    const float* cvb   = (const float*)d_in[6];
    const float* cow   = (const float*)d_in[7];
    const float* cob   = (const float*)d_in[8];
    const float* tbk   = (const float*)d_in[9];
    const float* tbv   = (const float*)d_in[10];

    // ws layout (bytes). Alias: x = wkT (wkT last read by k_gemm2, before
    // k_convv2 writes x). xmix has its own region (ws is 512 MB).
    char* wsb = (char*)d_ws;
    float* q    = (float*)(wsb + 0);         //   16384 f32
    float* k    = (float*)(wsb + 65536);     //  131072 f32
    short* q_a  = (short*)(wsb + 598016);    //  262144 bf16
    short* k_a  = (short*)(wsb + 1122304);   // 2097152 bf16
    short* wvT  = (short*)(wsb + 5316608);   //  147456 bf16
    short* woT  = (short*)(wsb + 5611520);   //   73728 bf16
    short* wkT  = (short*)(wsb + 5758976);   // 4194304 bf16
    short* wqT  = (short*)(wsb + 14147584);  // 4194304 bf16
    short* xmix = (short*)(wsb + 22536192);  // 32*8*6*4096 = 12582912 bf16 (24 MB)
    short* x    = wkT;                       // alias (see above)

    k_prep<<<PB_WO, 256, 0, stream>>>(inp, k_ant, w_q, w_k, cvw, cow,
                                      q, q_a, k_a, wqT, wkT, wvT, woT);
    k_gemm2<<<576, 256, 0, stream>>>(q_a, k_a, wqT, wkT, q, k);
    k_mix<<<1536, 256, 0, stream>>>(v_ant, q, k, tbk, xmix);
    k_convv2<<<256, 256, 0, stream>>>(xmix, wvT, cvb, tbv, q, k, tbk, x);
    k_convo_mfma<<<256, 256, 0, stream>>>(x, woT, cob, (float*)d_out);
}

// Round 5
// 395.608 us; speedup vs baseline: 1.0361x; 1.0179x over previous
//
#include <hip/hip_runtime.h>
#include <hip/hip_bf16.h>

typedef __hip_bfloat16 bf16;
typedef __attribute__((ext_vector_type(8))) short bf16x8;
typedef __attribute__((ext_vector_type(4))) float f32x4;

constexpr int B_ = 32, S_ = 8, H_ = 32, W_ = 32, C_ = 128;
constexpr int NH_ = 8, KD_ = 512, DKH_ = 64, VF_ = 128, OF_ = 64;
constexpr int QKIN_ = 8192;

static __device__ __forceinline__ short bfbits(float f) {
    bf16 h = __float2bfloat16(f);
    short s;
    __builtin_memcpy(&s, &h, 2);
    return s;
}
static __device__ __forceinline__ unsigned int packbf2(float a, float b) {
    return ((unsigned int)(unsigned short)bfbits(b) << 16) | (unsigned short)bfbits(a);
}

// async global->LDS, 16B per lane. LDS dest is wave-uniform base + lane*16;
// global src is per-lane. Data never touches VGPRs -> issue depth independent
// of register allocation (the r4 failure: VGPR=36 serialized reg batches).
static __device__ __forceinline__ void gl2lds16(const void* g, void* l) {
    __builtin_amdgcn_global_load_lds(
        (const __attribute__((address_space(1))) unsigned int*)g,
        (__attribute__((address_space(3))) unsigned int*)l, 16, 0, 0);
}

// ---------------- prep device functions ----------------

// transpose+cvt: w[K=8192][N=512] f32 -> wT[N][K] bf16. local in [0, 1024)
static __device__ __forceinline__ void dev_wT(const float* __restrict__ w,
                                              short* __restrict__ wT, int local,
                                              float (*t)[65]) {
    int k0 = (local >> 3) * 64, n0 = (local & 7) * 64;
    int c4 = (threadIdx.x & 15) * 4, r16 = threadIdx.x >> 4;
#pragma unroll
    for (int i = 0; i < 4; ++i) {
        int kr = i * 16 + r16;
        float4 v = *reinterpret_cast<const float4*>(
            w + (size_t)(k0 + kr) * KD_ + n0 + c4);
        t[kr][c4 + 0] = v.x;
        t[kr][c4 + 1] = v.y;
        t[kr][c4 + 2] = v.z;
        t[kr][c4 + 3] = v.w;
    }
    __syncthreads();
    int n = threadIdx.x >> 3, kg = threadIdx.x & 7;
#pragma unroll
    for (int half = 0; half < 2; ++half) {
        int nn = n + half * 32;
        short v[8];
#pragma unroll
        for (int j = 0; j < 8; ++j) v[j] = bfbits(t[kg * 8 + j][nn]);
        *reinterpret_cast<bf16x8*>(wT + (size_t)(n0 + nn) * QKIN_ + k0 + kg * 8) =
            *reinterpret_cast<bf16x8*>(v);
    }
}

// conv weight transpose: [tap][ci][CO] f32 -> [tap][co][CI] bf16
static __device__ __forceinline__ void dev_wtrans(const float* __restrict__ in,
                                                  short* __restrict__ out, int idx,
                                                  int CO) {
    int tap = idx / (128 * CO);
    int rem = idx % (128 * CO);
    int co = rem / 128;
    int ci = rem & 127;
    out[idx] = bfbits(in[((size_t)tap * 128 + ci) * CO + co]);
}

// ---------------- merged prep: zero | pool(inp+k_ant via global_load_lds)
//                  | wT(w_q) | wT(w_k) | wtrans_v | wtrans_o
constexpr int PB_ZERO = 144;
constexpr int PB_POOL = PB_ZERO + 2304;   // 288 imgs x 8 ph, 64 KB LDS strips
constexpr int PB_WTQ  = PB_POOL + 1024;
constexpr int PB_WTK  = PB_WTQ + 1024;
constexpr int PB_WV   = PB_WTK + 576;
constexpr int PB_WO   = PB_WV + 288;

__global__ __launch_bounds__(256) void k_prep(
    const float* __restrict__ inp, const float* __restrict__ k_ant,
    const float* __restrict__ w_q, const float* __restrict__ w_k,
    const float* __restrict__ cvw, const float* __restrict__ cow,
    float* __restrict__ qk_zero, short* __restrict__ q_a, short* __restrict__ k_a,
    short* __restrict__ wqT, short* __restrict__ wkT,
    short* __restrict__ wvT, short* __restrict__ woT) {
    __shared__ float4 smem[4096];  // 64 KB union: pool strip / wT tile
    int bx = blockIdx.x;
    if (bx < PB_ZERO) {
        int i = (bx * 256 + threadIdx.x) * 4;
        float4 z = {0.f, 0.f, 0.f, 0.f};
        *reinterpret_cast<float4*>(qk_zero + i) = z;
    } else if (bx < PB_POOL) {
        // pool: stage 4 rows (64 KB) via global_load_lds, then 4x4 avg from LDS
        int pb = bx - PB_ZERO;
        int img_g = pb >> 3, ph = pb & 7;
        const float* src;
        short* dst;
        int img;
        if (img_g < 32) { src = inp;   img = img_g;      dst = q_a; }
        else            { src = k_ant; img = img_g - 32; dst = k_a; }
        const float* base = src + ((size_t)img * H_ + ph * 4) * W_ * C_;
#pragma unroll
        for (int rnd = 0; rnd < 16; ++rnd) {
            int i = rnd * 256 + threadIdx.x;  // float4 granule in [0,4096)
            gl2lds16(base + (size_t)i * 4,
                     (char*)smem + ((i >> 6) << 6) * 16);
        }
        __syncthreads();
        int cg = threadIdx.x & 31, pw = threadIdx.x >> 5;
        float4 s = {0.f, 0.f, 0.f, 0.f};
#pragma unroll
        for (int dy = 0; dy < 4; ++dy)
#pragma unroll
            for (int dx = 0; dx < 4; ++dx) {
                float4 v = smem[(dy * 32 + pw * 4 + dx) * 32 + cg];
                s.x += v.x; s.y += v.y; s.z += v.z; s.w += v.w;
            }
        uint2 pk;
        pk.x = packbf2(s.x * 0.0625f, s.y * 0.0625f);
        pk.y = packbf2(s.z * 0.0625f, s.w * 0.0625f);
        *reinterpret_cast<uint2*>(dst + (size_t)img * QKIN_ +
                                  (ph * 8 + pw) * 128 + cg * 4) = pk;
    } else if (bx < PB_WTK) {
        float (*t)[65] = (float (*)[65])smem;
        if (bx < PB_WTQ)
            dev_wT(w_q, wqT, bx - PB_POOL, t);
        else
            dev_wT(w_k, wkT, bx - PB_WTQ, t);
    } else if (bx < PB_WV) {
        dev_wtrans(cvw, wvT, (bx - PB_WTK) * 256 + threadIdx.x, 128);
    } else {
        dev_wtrans(cow, woT, (bx - PB_WV) * 256 + threadIdx.x, 64);
    }
}

// ---------------- merged MFMA GEMM: q (M=32) and k (M=256), K-split 16.
__global__ __launch_bounds__(256) void k_gemm2(
    const short* __restrict__ qa, const short* __restrict__ ka,
    const short* __restrict__ wqTp, const short* __restrict__ wkTp,
    float* __restrict__ qo, float* __restrict__ ko) {
    int wave = threadIdx.x >> 6, lane = threadIdx.x & 63;
    int quad = lane >> 4, l15 = lane & 15;
    int id = blockIdx.x;
    const short* A;
    const short* WT;
    float* out;
    int m0, rem;
    if (id < 64) {
        A = qa; WT = wqTp; out = qo; m0 = 0; rem = id;
    } else {
        id -= 64;
        A = ka; WT = wkTp; out = ko;
        m0 = (id >> 6) * 32; rem = id & 63;
    }
    int n0 = (rem & 3) * 128 + wave * 32;
    int k0 = (rem >> 2) * 512;
    f32x4 acc[2][2];
#pragma unroll
    for (int mt = 0; mt < 2; ++mt)
#pragma unroll
        for (int nt = 0; nt < 2; ++nt) acc[mt][nt] = (f32x4){0.f, 0.f, 0.f, 0.f};
    const short* a0p = A + (size_t)(m0 + l15) * QKIN_;
    const short* a1p = a0p + 16 * QKIN_;
    const short* b0p = WT + (size_t)(n0 + l15) * QKIN_;
    const short* b1p = b0p + 16 * QKIN_;
    for (int kk = k0 + quad * 8; kk < k0 + 512; kk += 32) {
        bf16x8 a0 = *reinterpret_cast<const bf16x8*>(a0p + kk);
        bf16x8 a1 = *reinterpret_cast<const bf16x8*>(a1p + kk);
        bf16x8 b0 = *reinterpret_cast<const bf16x8*>(b0p + kk);
        bf16x8 b1 = *reinterpret_cast<const bf16x8*>(b1p + kk);
        acc[0][0] = __builtin_amdgcn_mfma_f32_16x16x32_bf16(a0, b0, acc[0][0], 0, 0, 0);
        acc[0][1] = __builtin_amdgcn_mfma_f32_16x16x32_bf16(a0, b1, acc[0][1], 0, 0, 0);
        acc[1][0] = __builtin_amdgcn_mfma_f32_16x16x32_bf16(a1, b0, acc[1][0], 0, 0, 0);
        acc[1][1] = __builtin_amdgcn_mfma_f32_16x16x32_bf16(a1, b1, acc[1][1], 0, 0, 0);
    }
#pragma unroll
    for (int mt = 0; mt < 2; ++mt)
#pragma unroll
        for (int nt = 0; nt < 2; ++nt)
#pragma unroll
            for (int reg = 0; reg < 4; ++reg)
                atomicAdd(&out[(size_t)(m0 + mt * 16 + quad * 4 + reg) * KD_ +
                               n0 + nt * 16 + l15],
                          acc[mt][nt][reg]);
}

// ---------------- softmax helper: wave 0 computes w8s[8] for (b,h)
static __device__ __forceinline__ void dev_softmax(
    const float* __restrict__ q, const float* __restrict__ kmat,
    const float* __restrict__ tbk, int b, int h, float* w8s) {
    if (threadIdx.x < 64) {
        int d = threadIdx.x;
        float qv = q[(size_t)b * KD_ + h * DKH_ + d];
        float lg[8];
        float m = -1e30f;
#pragma unroll
        for (int s = 0; s < 8; ++s) {
            int zi = (s < 4) ? 0 : (s - 4);
            float kv = kmat[((size_t)b * S_ + s) * KD_ + h * DKH_ + d] + tbk[zi * DKH_ + d];
            float p = qv * kv * 0.125f;
#pragma unroll
            for (int msk = 1; msk < 64; msk <<= 1) p += __shfl_xor(p, msk);
            lg[s] = p;
            m = fmaxf(m, p);
        }
        float sum = 0.f;
#pragma unroll
        for (int s = 0; s < 8; ++s) {
            lg[s] = expf(lg[s] - m);
            sum += lg[s];
        }
        if (d == 0) {
            float inv = 1.f / sum;
#pragma unroll
            for (int s = 0; s < 8; ++s) w8s[s] = lg[s] * inv;
        }
    }
}

// ---------------- k_mix: streaming softmax-mix of v_ant into per-head 6-row
// halo strips, staged through LDS via global_load_lds (8 planes in flight).
// block = (b, h, r, quarter): 6144 blocks, 32 KB LDS each (4 blocks/CU).
__global__ __launch_bounds__(256) void k_mix(
    const float* __restrict__ v_ant, const float* __restrict__ q,
    const float* __restrict__ kmat, const float* __restrict__ tbk,
    short* __restrict__ xmix) {
    __shared__ float4 smem[2048];  // 32 KB: [8 s-planes][256 granules]
    __shared__ float w8s[8];
    int bx = blockIdx.x;
    int qtr = bx & 3;
    int r = (bx >> 2) % 6;
    int hb = (bx >> 2) / 6;  // b*8 + h
    int h = hb & 7, b = hb >> 3;
    int yimg = 4 * h - 1 + r;
    short* outp = xmix + ((size_t)hb * 6 + r) * 4096 + qtr * 1024;
    if (yimg < 0 || yimg >= H_) {
        uint2 z = {0u, 0u};
        *reinterpret_cast<uint2*>(outp + threadIdx.x * 4) = z;
        return;
    }
    dev_softmax(q, kmat, tbk, b, h, w8s);
    const float* base = v_ant + (size_t)b * 1048576 + yimg * 4096 + qtr * 1024;
#pragma unroll
    for (int s = 0; s < 8; ++s) {
        int i = s * 256 + threadIdx.x;
        gl2lds16(base + (size_t)s * 131072 + threadIdx.x * 4,
                 (char*)smem + ((i >> 6) << 6) * 16);
    }
    __syncthreads();
    float w8[8];
#pragma unroll
    for (int s = 0; s < 8; ++s) w8[s] = w8s[s];
    float4 a = {0.f, 0.f, 0.f, 0.f};
#pragma unroll
    for (int s = 0; s < 8; ++s) {
        float4 v = smem[s * 256 + threadIdx.x];
        a.x = fmaf(w8[s], v.x, a.x);
        a.y = fmaf(w8[s], v.y, a.y);
        a.z = fmaf(w8[s], v.z, a.z);
        a.w = fmaf(w8[s], v.w, a.w);
    }
    uint2 pk;
    pk.x = packbf2(a.x, a.y);
    pk.y = packbf2(a.z, a.w);
    *reinterpret_cast<uint2*>(outp + threadIdx.x * 4) = pk;
}

// ---------------- staging: contiguous 6-row pre-mixed strip -> padded LDS strip.
static __device__ __forceinline__ void dev_stage_copy(const short* __restrict__ src,
                                                      short* __restrict__ strip) {
    for (int i = threadIdx.x; i < 384; i += 256) {
        int r = i >> 6, remz = i & 63;
        int side = remz >> 5, cg = remz & 31;
        uint2 z = {0u, 0u};
        *reinterpret_cast<uint2*>(&strip[(r * 34 + side * 33) * 136 + cg * 4]) = z;
    }
#pragma unroll
    for (int round = 0; round < 3; ++round) {
        uint2 vv[8];
#pragma unroll
        for (int j = 0; j < 8; ++j) {
            int i = (round * 8 + j) * 256 + threadIdx.x;
            vv[j] = *reinterpret_cast<const uint2*>(src + i * 4);
        }
#pragma unroll
        for (int j = 0; j < 8; ++j) {
            int i = (round * 8 + j) * 256 + threadIdx.x;
            int r = i >> 10, rem = i & 1023;
            int px = rem >> 5, cg = rem & 31;
            *reinterpret_cast<uint2*>(&strip[(r * 34 + px + 1) * 136 + cg * 4]) = vv[j];
        }
    }
}

// ---------------- strip staging with row-bounds checks (for conv_o over x).
static __device__ __forceinline__ void dev_stage6(const short* __restrict__ src,
                                                  int y0, short* __restrict__ strip) {
    for (int i = threadIdx.x; i < 384; i += 256) {
        int r = i >> 6, remz = i & 63;
        int side = remz >> 5, cg = remz & 31;
        uint2 z = {0u, 0u};
        *reinterpret_cast<uint2*>(&strip[(r * 34 + side * 33) * 136 + cg * 4]) = z;
    }
#pragma unroll
    for (int round = 0; round < 3; ++round) {
        uint2 vv[8];
#pragma unroll
        for (int j = 0; j < 8; ++j) {
            int i = (round * 8 + j) * 256 + threadIdx.x;
            int r = i >> 10, rem = i & 1023;
            int yimg = y0 - 1 + r;
            vv[j] = (uint2){0u, 0u};
            if (0 <= yimg && yimg < H_)
                vv[j] = *reinterpret_cast<const uint2*>(src + yimg * 4096 + rem * 4);
        }
#pragma unroll
        for (int j = 0; j < 8; ++j) {
            int i = (round * 8 + j) * 256 + threadIdx.x;
            int r = i >> 10, rem = i & 1023;
            int px = rem >> 5, cg = rem & 31;
            *reinterpret_cast<uint2*>(&strip[(r * 34 + px + 1) * 136 + cg * 4]) = vv[j];
        }
    }
}

// ---------------- conv_v GEMM over per-head pre-mixed strips. block=(b,h).
__global__ __launch_bounds__(256) void k_convv2(
    const short* __restrict__ xmix, const short* __restrict__ wvT,
    const float* __restrict__ bias, const float* __restrict__ tbv,
    const float* __restrict__ q, const float* __restrict__ kmat,
    const float* __restrict__ tbk, short* __restrict__ x) {
    __shared__ short strip[6 * 34 * 136];  // 55488 B
    __shared__ float w8s[8];
    int b = blockIdx.x >> 3, h = blockIdx.x & 7;
    int y0 = 4 * h;
    dev_softmax(q, kmat, tbk, b, h, w8s);
    dev_stage_copy(xmix + (size_t)(b * 8 + h) * 6 * 4096, strip);
    __syncthreads();
    int wave = threadIdx.x >> 6, lane = threadIdx.x & 63;
    int quad = lane >> 4, l15 = lane & 15;
    int n0 = wave * 32;
    f32x4 acc[8][2];
#pragma unroll
    for (int mt = 0; mt < 8; ++mt)
#pragma unroll
        for (int nt = 0; nt < 2; ++nt) acc[mt][nt] = (f32x4){0.f, 0.f, 0.f, 0.f};
    for (int kc = 0; kc < 36; ++kc) {
        int tap = kc >> 2;
        int ci0 = (kc & 3) * 32 + quad * 8;
        int ky = tap / 3, dx = tap % 3;
        bf16x8 bfr[2];
#pragma unroll
        for (int nt = 0; nt < 2; ++nt) {
            int co = n0 + nt * 16 + l15;
            bfr[nt] = *reinterpret_cast<const bf16x8*>(
                wvT + ((size_t)tap * 128 + co) * 128 + ci0);
        }
#pragma unroll
        for (int mt = 0; mt < 8; ++mt) {
            int jout = mt >> 1, half = mt & 1;
            int r = jout + ky;
            int px1 = half * 16 + l15 + dx;
            bf16x8 afr = *reinterpret_cast<const bf16x8*>(
                &strip[(r * 34 + px1) * 136 + ci0]);
            acc[mt][0] = __builtin_amdgcn_mfma_f32_16x16x32_bf16(afr, bfr[0], acc[mt][0], 0, 0, 0);
            acc[mt][1] = __builtin_amdgcn_mfma_f32_16x16x32_bf16(afr, bfr[1], acc[mt][1], 0, 0, 0);
        }
    }
    float cw[4];
    cw[0] = w8s[0] + w8s[1] + w8s[2] + w8s[3] + w8s[4];
    cw[1] = w8s[5];
    cw[2] = w8s[6];
    cw[3] = w8s[7];
#pragma unroll
    for (int mt = 0; mt < 8; ++mt) {
        int jout = mt >> 1, half = mt & 1;
#pragma unroll
        for (int nt = 0; nt < 2; ++nt) {
            int co = n0 + nt * 16 + l15;
            float bv = bias[co];
#pragma unroll
            for (int reg = 0; reg < 4; ++reg) {
                int px = half * 16 + quad * 4 + reg;
                int d = jout * 4096 + px * 128 + co;
                float v = acc[mt][nt][reg] + bv;
                v = fmaf(cw[0], tbv[d], v);
                v = fmaf(cw[1], tbv[16384 + d], v);
                v = fmaf(cw[2], tbv[32768 + d], v);
                v = fmaf(cw[3], tbv[49152 + d], v);
                x[(((size_t)b * H_ + y0 + jout) * W_ + px) * C_ + co] = bfbits(v);
            }
        }
    }
}

// ---------------- conv_o via MFMA. block=(b, rowgroup of 4), 4-row groups.
__global__ __launch_bounds__(256) void k_convo_mfma(
    const short* __restrict__ x, const short* __restrict__ woT,
    const float* __restrict__ bias, float* __restrict__ out) {
    __shared__ short strip[6 * 34 * 136];
    int b = blockIdx.x >> 3, rg = blockIdx.x & 7;
    int y0 = 4 * rg;
    dev_stage6(x + (size_t)b * 131072, y0, strip);
    __syncthreads();
    int wave = threadIdx.x >> 6, lane = threadIdx.x & 63;
    int quad = lane >> 4, l15 = lane & 15;
    int co = wave * 16 + l15;
    f32x4 acc[8];
#pragma unroll
    for (int mt = 0; mt < 8; ++mt) acc[mt] = (f32x4){0.f, 0.f, 0.f, 0.f};
    for (int kc = 0; kc < 36; ++kc) {
        int tap = kc >> 2;
        int ci0 = (kc & 3) * 32 + quad * 8;
        int ky = tap / 3, dx = tap % 3;
        bf16x8 bfr = *reinterpret_cast<const bf16x8*>(
            woT + ((size_t)tap * 64 + co) * 128 + ci0);
#pragma unroll
        for (int mt = 0; mt < 8; ++mt) {
            int jout = mt >> 1, half = mt & 1;
            int r = jout + ky;
            int px1 = half * 16 + l15 + dx;
            bf16x8 afr = *reinterpret_cast<const bf16x8*>(
                &strip[(r * 34 + px1) * 136 + ci0]);
            acc[mt] = __builtin_amdgcn_mfma_f32_16x16x32_bf16(afr, bfr, acc[mt], 0, 0, 0);
        }
    }
    float bv = bias[co];
#pragma unroll
    for (int mt = 0; mt < 8; ++mt) {
        int jout = mt >> 1, half = mt & 1;
#pragma unroll
        for (int reg = 0; reg < 4; ++reg) {
            int px = half * 16 + quad * 4 + reg;
            out[(((size_t)b * H_ + y0 + jout) * W_ + px) * OF_ + co] = acc[mt][reg] + bv;
        }
    }
}

extern "C" void kernel_launch(void* const* d_in, const int* in_sizes, int n_in,
                              void* d_out, int out_size, void* d_ws, size_t ws_size,
                              hipStream_t stream) {
    const float* inp   = (const float*)d_in[0];
    const float* k_ant = (const float*)d_in[1];
    const float* v_ant = (const float*)d_in[2];
    const float* w_q   = (const float*)d_in[3];
    const float* w_k   = (const float*)d_in[4];
    const float* cvw   = (const float*)d_in[5];
    const float* cvb   = (const float*)d_in[6];
    const float* cow   = (const float*)d_in[7];
    const float* cob   = (const float*)d_in[8];
    const float* tbk   = (const float*)d_in[9];
    const float* tbv   = (const float*)d_in[10];

    // ws layout (bytes). Alias: x = wkT (wkT last read by k_gemm2, before
    // k_convv2 writes x). xmix has its own region.
    char* wsb = (char*)d_ws;
    float* q    = (float*)(wsb + 0);         //   16384 f32
    float* k    = (float*)(wsb + 65536);     //  131072 f32
    short* q_a  = (short*)(wsb + 598016);    //  262144 bf16
    short* k_a  = (short*)(wsb + 1122304);   // 2097152 bf16
    short* wvT  = (short*)(wsb + 5316608);   //  147456 bf16
    short* woT  = (short*)(wsb + 5611520);   //   73728 bf16
    short* wkT  = (short*)(wsb + 5758976);   // 4194304 bf16
    short* wqT  = (short*)(wsb + 14147584);  // 4194304 bf16
    short* xmix = (short*)(wsb + 22536192);  // 32*8*6*4096 bf16 (24 MB)
    short* x    = wkT;                       // alias (see above)

    k_prep<<<PB_WO, 256, 0, stream>>>(inp, k_ant, w_q, w_k, cvw, cow,
                                      q, q_a, k_a, wqT, wkT, wvT, woT);
    k_gemm2<<<576, 256, 0, stream>>>(q_a, k_a, wqT, wkT, q, k);
    k_mix<<<6144, 256, 0, stream>>>(v_ant, q, k, tbk, xmix);
    k_convv2<<<256, 256, 0, stream>>>(xmix, wvT, cvb, tbv, q, k, tbk, x);
    k_convo_mfma<<<256, 256, 0, stream>>>(x, woT, cob, (float*)d_out);
}